// Round 9
// baseline (1244.786 us; speedup 1.0000x reference)
//
#include <hip/hip_runtime.h>
#include <hip/hip_bf16.h>
#include <math.h>

// Problem constants
#define B_SZ   8
#define SEQ    2048
#define DMODEL 512
#define DEPTH  2
#define DSTATE 16
#define DCONV  4
#define DINNER 1024
#define DTRANK 32
#define ROWS   (B_SZ * SEQ)          // 16384
#define DBCW   (DTRANK + 2 * DSTATE) // 64

typedef unsigned short u16;
typedef float f32x4 __attribute__((ext_vector_type(4)));
typedef short bf16x8 __attribute__((ext_vector_type(8)));

// Fast device math (native v_exp/v_log/v_rcp)
__device__ __forceinline__ float silu_f(float v) {
    return v * __builtin_amdgcn_rcpf(1.f + __expf(-v));
}
__device__ __forceinline__ float softplus_f(float s) {
    return (s > 20.f) ? s : __logf(1.f + __expf(s));
}
__device__ __forceinline__ u16 f2b(float v) {
    __hip_bfloat16 h = __float2bfloat16(v);
    return *(u16*)&h;
}
__device__ __forceinline__ float b2f(u16 v) {
    __hip_bfloat16 h;
    *(u16*)&h = v;
    return __bfloat162float(h);
}
// sum across the 16-lane state group (DPP row rotate-reduce)
__device__ __forceinline__ float sum16(float x) {
    x += __int_as_float(__builtin_amdgcn_update_dpp(0, __float_as_int(x), 0x121, 0xf, 0xf, true));
    x += __int_as_float(__builtin_amdgcn_update_dpp(0, __float_as_int(x), 0x122, 0xf, 0xf, true));
    x += __int_as_float(__builtin_amdgcn_update_dpp(0, __float_as_int(x), 0x124, 0xf, 0xf, true));
    x += __int_as_float(__builtin_amdgcn_update_dpp(0, __float_as_int(x), 0x128, 0xf, 0xf, true));
    return x;
}

__device__ __forceinline__ void load_lds16(const void* g, void* l) {
    __builtin_amdgcn_global_load_lds(
        (const __attribute__((address_space(1))) unsigned int*)g,
        (__attribute__((address_space(3))) unsigned int*)l, 16, 0, 0);
}

// ---------------------------------------------------------------- fp32 -> bf16 convert
__global__ __launch_bounds__(256) void f2bf(const float* __restrict__ in,
                                            __hip_bfloat16* __restrict__ out, int n) {
    int i = blockIdx.x * 256 + threadIdx.x;
    if (i < n) out[i] = __float2bfloat16(in[i]);
}

// ---------------------------------------------------------------- LayerNorm (bf16 out)
__global__ __launch_bounds__(256) void ln_kernel(const float* __restrict__ x,
                                                 const float* __restrict__ w,
                                                 const float* __restrict__ b,
                                                 __hip_bfloat16* __restrict__ out) {
    int r = blockIdx.x;
    int tid = threadIdx.x;
    const float* xr = x + (size_t)r * DMODEL;
    float2 v = *(const float2*)(xr + tid * 2);
    float s = v.x + v.y;
    float s2 = v.x * v.x + v.y * v.y;
    #pragma unroll
    for (int off = 1; off < 64; off <<= 1) {
        s  += __shfl_xor(s, off);
        s2 += __shfl_xor(s2, off);
    }
    __shared__ float ws[4], ws2[4];
    int wid = tid >> 6, lane = tid & 63;
    if (lane == 0) { ws[wid] = s; ws2[wid] = s2; }
    __syncthreads();
    float ts = ws[0] + ws[1] + ws[2] + ws[3];
    float ts2 = ws2[0] + ws2[1] + ws2[2] + ws2[3];
    float mean = ts * (1.f / DMODEL);
    float var = ts2 * (1.f / DMODEL) - mean * mean;
    float inv = rsqrtf(var + 1e-5f);
    out[(size_t)r * DMODEL + tid * 2]     = __float2bfloat16((v.x - mean) * inv * w[tid * 2] + b[tid * 2]);
    out[(size_t)r * DMODEL + tid * 2 + 1] = __float2bfloat16((v.y - mean) * inv * w[tid * 2 + 1] + b[tid * 2 + 1]);
}

// ---------------------------------------------------------------- bf16 MFMA GEMM
// C(MxN fp32) = A(MxK bf16, row pitch lda) * W(NxK bf16)^T (+res fp32)
template <bool RES>
__global__ __launch_bounds__(256) void gemm_bf16(const u16* __restrict__ A, int lda,
                                                 const u16* __restrict__ W,
                                                 const float* __restrict__ res,
                                                 float* __restrict__ C,
                                                 int M, int N, int K) {
    __shared__ u16 As[128 * 32];
    __shared__ u16 Bs[128 * 32];
    int tid = threadIdx.x;
    int wave = tid >> 6, lane = tid & 63;
    int wm = (wave >> 1) * 64, wn = (wave & 1) * 64;
    int m0 = blockIdx.y * 128, n0 = blockIdx.x * 128;
    int srow = lane >> 2, sseg = lane & 3;
    const u16* Ag = A + (size_t)(m0 + wave * 32 + srow) * lda + sseg * 8;
    const u16* Wg = W + (size_t)(n0 + wave * 32 + srow) * K + sseg * 8;
    u16* Asw = As + wave * 32 * 32;
    u16* Bsw = Bs + wave * 32 * 32;

    f32x4 acc[4][4] = {};
    int col = lane & 15, quad = lane >> 4;

    for (int k0 = 0; k0 < K; k0 += 32) {
        __syncthreads();
        load_lds16(Ag + k0, Asw);
        load_lds16(Ag + k0 + (size_t)16 * lda, Asw + 16 * 32);
        load_lds16(Wg + k0, Bsw);
        load_lds16(Wg + k0 + (size_t)16 * K, Bsw + 16 * 32);
        __syncthreads();
        bf16x8 af[4], bfr[4];
        #pragma unroll
        for (int i = 0; i < 4; ++i) {
            af[i]  = *(const bf16x8*)(As + (wm + i * 16 + col) * 32 + quad * 8);
            bfr[i] = *(const bf16x8*)(Bs + (wn + i * 16 + col) * 32 + quad * 8);
        }
        #pragma unroll
        for (int i = 0; i < 4; ++i)
            #pragma unroll
            for (int j = 0; j < 4; ++j)
                acc[i][j] = __builtin_amdgcn_mfma_f32_16x16x32_bf16(af[i], bfr[j], acc[i][j], 0, 0, 0);
    }
    #pragma unroll
    for (int i = 0; i < 4; ++i) {
        int gm_base = m0 + wm + i * 16 + quad * 4;
        #pragma unroll
        for (int j = 0; j < 4; ++j) {
            int gn = n0 + wn + j * 16 + col;
            #pragma unroll
            for (int r = 0; r < 4; ++r) {
                size_t off = (size_t)(gm_base + r) * N + gn;
                float v = acc[i][j][r];
                if (RES) v += res[off];
                C[off] = v;
            }
        }
    }
}

// ---------------------------------------------------------------- x_proj bf16 MFMA GEMM (N=64)
__global__ __launch_bounds__(256) void gemm_xp_bf16(const u16* __restrict__ A,
                                                    const u16* __restrict__ W,
                                                    float* __restrict__ C) {
    __shared__ u16 As[128 * 32];
    __shared__ u16 Bs[64 * 32];
    int tid = threadIdx.x;
    int wave = tid >> 6, lane = tid & 63;
    int m0 = blockIdx.x * 128;
    int wm = wave * 32;
    int srow = lane >> 2, sseg = lane & 3;
    const u16* Ag = A + (size_t)(m0 + wm + srow) * DINNER + sseg * 8;
    const u16* Wg = W + (size_t)(wave * 16 + srow) * DINNER + sseg * 8;
    u16* Asw = As + wave * 32 * 32;
    u16* Bsw = Bs + wave * 16 * 32;

    f32x4 acc[2][4] = {};
    int col = lane & 15, quad = lane >> 4;

    for (int k0 = 0; k0 < DINNER; k0 += 32) {
        __syncthreads();
        load_lds16(Ag + k0, Asw);
        load_lds16(Ag + k0 + (size_t)16 * DINNER, Asw + 16 * 32);
        load_lds16(Wg + k0, Bsw);
        __syncthreads();
        bf16x8 af[2], bfr[4];
        #pragma unroll
        for (int i = 0; i < 2; ++i)
            af[i] = *(const bf16x8*)(As + (wm + i * 16 + col) * 32 + quad * 8);
        #pragma unroll
        for (int j = 0; j < 4; ++j)
            bfr[j] = *(const bf16x8*)(Bs + (j * 16 + col) * 32 + quad * 8);
        #pragma unroll
        for (int i = 0; i < 2; ++i)
            #pragma unroll
            for (int j = 0; j < 4; ++j)
                acc[i][j] = __builtin_amdgcn_mfma_f32_16x16x32_bf16(af[i], bfr[j], acc[i][j], 0, 0, 0);
    }
    #pragma unroll
    for (int i = 0; i < 2; ++i) {
        int gm_base = m0 + wm + i * 16 + quad * 4;
        #pragma unroll
        for (int j = 0; j < 4; ++j) {
            int gn = j * 16 + col;
            #pragma unroll
            for (int r = 0; r < 4; ++r)
                C[(size_t)(gm_base + r) * DBCW + gn] = acc[i][j][r];
        }
    }
}

// ---------------------------------------------------------------- u precompute (ut [b,e,t] + u_re [r,e])
__global__ __launch_bounds__(256) void u_t_kernel(const float* __restrict__ xz,
                                                  const float* __restrict__ cw,
                                                  const float* __restrict__ cb,
                                                  u16* __restrict__ ut,
                                                  u16* __restrict__ u_re) {
    __shared__ float xt[67][65];
    __shared__ u16 uo[64][70];
    int tid = threadIdx.x;
    int t0 = blockIdx.x * 64, e0 = blockIdx.y * 64, b = blockIdx.z;
    int er = tid & 63, rr = tid >> 6;
    for (int it = 0; it < 17; ++it) {
        int row = it * 4 + rr;
        if (row < 67) {
            int t = t0 + row - 3;
            xt[row][er] = (t >= 0) ? xz[((size_t)b * SEQ + t) * (2 * DINNER) + e0 + er] : 0.f;
        }
    }
    __syncthreads();
    {
        int e = tid & 63, tg = tid >> 6;
        float4 w4 = *(const float4*)(cw + (e0 + e) * 4);
        float cbe = cb[e0 + e];
        int tl0 = tg * 16;
        float x3 = xt[tl0][e], x2 = xt[tl0 + 1][e], x1 = xt[tl0 + 2][e];
        #pragma unroll
        for (int i = 0; i < 16; ++i) {
            float x0 = xt[tl0 + i + 3][e];
            float u = silu_f(cbe + w4.x * x3 + w4.y * x2 + w4.z * x1 + w4.w * x0);
            x3 = x2; x2 = x1; x1 = x0;
            u16 ub = f2b(u);
            uo[e][tl0 + i] = ub;
            u_re[((size_t)b * SEQ + t0 + tl0 + i) * DINNER + e0 + e] = ub;
        }
    }
    __syncthreads();
    {
        int tl = tid & 63, eg = tid >> 6;
        #pragma unroll
        for (int i = 0; i < 16; ++i) {
            int ee = eg * 16 + i;
            ut[((size_t)b * DINNER + e0 + ee) * SEQ + t0 + tl] = uo[ee][tl];
        }
    }
}

// ---------------------------------------------------------------- delta + B/C precompute (merged)
// dlt[b,e,t] = softplus(dt . dtw + dtb); e0==0 blocks also write Bt/Ct [b,n,t].
__global__ __launch_bounds__(256) void delta_bct_kernel(const float* __restrict__ dbc,
                                                        const float* __restrict__ dtw,
                                                        const float* __restrict__ dtb,
                                                        u16* __restrict__ dlt,
                                                        u16* __restrict__ Bt,
                                                        u16* __restrict__ Ct) {
    __shared__ float wl[64 * 32];
    __shared__ float bl[64];
    int tid = threadIdx.x;
    int e0 = blockIdx.x * 64, t0 = blockIdx.y * 256, b = blockIdx.z;
    for (int i = tid; i < 64 * 32; i += 256) wl[i] = dtw[(size_t)e0 * DTRANK + i];
    if (tid < 64) bl[tid] = dtb[e0 + tid];
    float dreg[32];
    const float* dp = dbc + (size_t)(b * SEQ + t0 + tid) * DBCW;
    #pragma unroll
    for (int k = 0; k < 32; k += 4) {
        float4 v = *(const float4*)(dp + k);
        dreg[k] = v.x; dreg[k + 1] = v.y; dreg[k + 2] = v.z; dreg[k + 3] = v.w;
    }
    __syncthreads();
    for (int ep = 0; ep < 64; ++ep) {
        float s = bl[ep];
        #pragma unroll
        for (int k = 0; k < 32; ++k) s += dreg[k] * wl[ep * 32 + k];
        dlt[((size_t)b * DINNER + e0 + ep) * SEQ + t0 + tid] = f2b(softplus_f(s));
    }
    if (blockIdx.x == 0) {
        int t = t0 + tid;
        const float* dp2 = dbc + (size_t)(b * SEQ + t) * DBCW + DTRANK;
        #pragma unroll
        for (int nn = 0; nn < DSTATE; ++nn) {
            Bt[((size_t)b * DSTATE + nn) * SEQ + t] = f2b(dp2[nn]);
            Ct[((size_t)b * DSTATE + nn) * SEQ + t] = f2b(dp2[DSTATE + nn]);
        }
    }
}

// ---------------------------------------------------------------- K1: half-sequence scan
// 1024 blocks = 512 pair-groups x 2 halves -> 4 blocks/CU (2x TLP vs single scan).
// Both halves start h=0; half 0 writes its final h to carry (fp32 [pg*256+tid]).
// Writes yraw = yp + u*D (fp32) into the dead xi slots of xz.
#define SCHUNK 8

__global__ __launch_bounds__(256, 4) void scan_half(float* xz,
                                                    const u16* __restrict__ ut,
                                                    const u16* __restrict__ dlt,
                                                    const u16* __restrict__ Bt,
                                                    const u16* __restrict__ Ct,
                                                    const float* __restrict__ Alog,
                                                    const float* __restrict__ Dp,
                                                    float* __restrict__ carry) {
    int tid = threadIdx.x;
    int pair = tid >> 4, n = tid & 15;
    int pg = blockIdx.x >> 1, half = blockIdx.x & 1;
    int b = pg >> 6;
    int e = ((pg & 63) << 4) + pair;
    int t_off = half << 10;
    float a = -__expf(Alog[e * DSTATE + n]);
    float dpe = Dp[e];
    const u16* urow  = ut  + ((size_t)b * DINNER + e) * SEQ + t_off;
    const u16* dlrow = dlt + ((size_t)b * DINNER + e) * SEQ + t_off;
    const u16* Brow  = Bt + ((size_t)b * DSTATE + n) * SEQ + t_off;
    const u16* Crow  = Ct + ((size_t)b * DSTATE + n) * SEQ + t_off;
    float* yrow = xz + ((size_t)b * SEQ + t_off) * (2 * DINNER) + e;

    float h = 0.f;
    bf16x8 Au, Adl, AB, AC, Bu, Bdl, BB, BC;

    auto load = [&](int c, bf16x8& u8, bf16x8& d8, bf16x8& b8, bf16x8& c8) {
        u8 = *(const bf16x8*)(urow + c * SCHUNK);
        d8 = *(const bf16x8*)(dlrow + c * SCHUNK);
        b8 = *(const bf16x8*)(Brow + c * SCHUNK);
        c8 = *(const bf16x8*)(Crow + c * SCHUNK);
    };
    auto proc = [&](int c, bf16x8 u8, bf16x8 d8, bf16x8 b8, bf16x8 c8) {
        float* yp_ = yrow + (size_t)c * SCHUNK * (2 * DINNER);
        #pragma unroll
        for (int j = 0; j < SCHUNK; ++j) {
            float uf = b2f((u16)u8[j]);
            float dl = b2f((u16)d8[j]);
            float dA = __expf(dl * a);
            h = dA * h + (dl * uf) * b2f((u16)b8[j]);
            float yp = sum16(h * b2f((u16)c8[j]));
            if (n == 0) yp_[(size_t)j * (2 * DINNER)] = yp + uf * dpe;
        }
    };

    const int nc = 1024 / SCHUNK;   // 128, even
    load(0, Au, Adl, AB, AC);
    for (int c = 0; c < nc; c += 2) {
        load(c + 1, Bu, Bdl, BB, BC);
        proc(c, Au, Adl, AB, AC);
        if (c + 2 < nc) load(c + 2, Au, Adl, AB, AC);
        proc(c + 1, Bu, Bdl, BB, BC);
    }
    if (half == 0) carry[pg * 256 + tid] = h;
}

// ---------------------------------------------------------------- cumsum of dl over second half
// St[row, ti] = sum_{s=1024..1024+ti} dl[row, s]  (inclusive, fp32). 8192 blocks (one row each).
__global__ __launch_bounds__(256) void cumsum_kernel(const u16* __restrict__ dlt,
                                                     float* __restrict__ St) {
    int row = blockIdx.x;
    int tid = threadIdx.x;
    const u16* dp = dlt + (size_t)row * SEQ + 1024;
    ushort4 d4 = *(const ushort4*)(dp + tid * 4);
    float s1 = b2f(d4.x);
    float s2 = s1 + b2f(d4.y);
    float s3 = s2 + b2f(d4.z);
    float s4 = s3 + b2f(d4.w);
    __shared__ float ts[256];
    ts[tid] = s4;
    __syncthreads();
    float acc = s4;
    for (int off = 1; off < 256; off <<= 1) {
        float v = (tid >= off) ? ts[tid - off] : 0.f;
        __syncthreads();
        acc += v;
        ts[tid] = acc;
        __syncthreads();
    }
    float base = acc - s4;
    float4 o = {base + s1, base + s2, base + s3, base + s4};
    *(float4*)(St + (size_t)row * 1024 + tid * 4) = o;
}

// ---------------------------------------------------------------- K2: parallel fixup of second half
// y[t] += sum_n C[t,n] * exp(a_n * S_t) * h_carry[n].  Fully parallel over t.
// grid 4096 = 512 pair-groups x 8 t-chunks of 128.
__global__ __launch_bounds__(256, 4) void fixup_kernel(float* xz,
                                                       const u16* __restrict__ Ct,
                                                       const float* __restrict__ St,
                                                       const float* __restrict__ carry,
                                                       const float* __restrict__ Alog) {
    int tid = threadIdx.x;
    int pair = tid >> 4, n = tid & 15;
    int pg = blockIdx.x >> 3, tc = blockIdx.x & 7;
    int b = pg >> 6;
    int e = ((pg & 63) << 4) + pair;
    float a = -__expf(Alog[e * DSTATE + n]);
    float h0 = carry[pg * 256 + tid];
    const u16* Crow = Ct + ((size_t)b * DSTATE + n) * SEQ + 1024 + tc * 128;
    const float* Srow = St + ((size_t)b * DINNER + e) * 1024 + tc * 128;
    float* yrow = xz + ((size_t)b * SEQ + 1024 + tc * 128) * (2 * DINNER) + e;

    for (int c = 0; c < 16; ++c) {
        bf16x8 C8 = *(const bf16x8*)(Crow + c * 8);
        float4 Sa = *(const float4*)(Srow + c * 8);
        float4 Sb = *(const float4*)(Srow + c * 8 + 4);
        float Sv[8] = {Sa.x, Sa.y, Sa.z, Sa.w, Sb.x, Sb.y, Sb.z, Sb.w};
        float* yp = yrow + (size_t)c * 8 * (2 * DINNER);
        #pragma unroll
        for (int j = 0; j < 8; ++j) {
            float g = __expf(a * Sv[j]) * h0;
            float corr = sum16(g * b2f((u16)C8[j]));
            if (n == 0) {
                float* addr = yp + (size_t)j * (2 * DINNER);
                *addr = *addr + corr;
            }
        }
    }
}

// ---------------------------------------------------------------- gate + in-place bf16 pack
__global__ __launch_bounds__(256) void gate_pack(float* xz) {
    int r = blockIdx.x, tid = threadIdx.x;
    float* row = xz + (size_t)r * (2 * DINNER);
    float4 yr = ((const float4*)row)[tid];
    float4 zz = ((const float4*)(row + DINNER))[tid];
    __syncthreads();   // all reads done before any packed write
    ushort4 o;
    o.x = f2b(yr.x * silu_f(zz.x));
    o.y = f2b(yr.y * silu_f(zz.y));
    o.z = f2b(yr.z * silu_f(zz.z));
    o.w = f2b(yr.w * silu_f(zz.w));
    ((ushort4*)row)[tid] = o;
}

// ---------------------------------------------------------------- launch
extern "C" void kernel_launch(void* const* d_in, const int* in_sizes, int n_in,
                              void* d_out, int out_size, void* d_ws, size_t ws_size,
                              hipStream_t stream) {
    const float* x_in   = (const float*)d_in[0];
    const float* ln_w   = (const float*)d_in[1];
    const float* ln_b   = (const float*)d_in[2];
    const float* inw    = (const float*)d_in[3];
    const float* convw  = (const float*)d_in[4];
    const float* convb  = (const float*)d_in[5];
    const float* xpw    = (const float*)d_in[6];
    const float* dtw    = (const float*)d_in[7];
    const float* dtb    = (const float*)d_in[8];
    const float* Alog   = (const float*)d_in[9];
    const float* Dp     = (const float*)d_in[10];
    const float* outw   = (const float*)d_in[11];
    float* out = (float*)d_out;

    // workspace carve-up — 212,860,928 B (proven footprint)
    char* p = (char*)d_ws;
    float* xz  = (float*)p;                 p += (size_t)ROWS * 2 * DINNER * 4;   // 134,217,728
    float* dbc = (float*)p;                 p += (size_t)ROWS * DBCW * 4;         //   4,194,304
    float* carry = dbc;                     // alias: dbc dead after delta_bct; carry written by K1
    u16*   dlt = (u16*)p;                   p += (size_t)B_SZ * DINNER * SEQ * 2; //  33,554,432
    u16*   u_re = dlt;                      // alias: u_re consumed by x_proj before delta writes dlt
    u16*   Bt  = (u16*)p;                   p += (size_t)B_SZ * DSTATE * SEQ * 2; //     524,288
    u16*   Ct  = (u16*)p;                   p += (size_t)B_SZ * DSTATE * SEQ * 2; //     524,288
    u16*   ut  = (u16*)p;                   p += (size_t)B_SZ * DINNER * SEQ * 2; //  33,554,432
    __hip_bfloat16* xnbf = (__hip_bfloat16*)ut;   // alias: xn dead before u_t writes ut
    float* St = (float*)ut;                 // alias: St written after K1 consumed ut (8*1024*1024*4 = 33.5MB)
    __hip_bfloat16* inwbf  = (__hip_bfloat16*)p;  p += (size_t)2 * DINNER * DMODEL * 2; // 4,194,304
    u16* xwbf = (u16*)inwbf;                // alias: xpw-bf16 written AFTER in_proj consumes inwbf
    __hip_bfloat16* outwbf = (__hip_bfloat16*)p;  p += (size_t)DMODEL * DINNER * 2;     // 2,097,152

    const dim3 blk256(256);
    const int n_inw  = 2 * DINNER * DMODEL;
    const int n_outw = DMODEL * DINNER;
    const int n_xw   = DBCW * DINNER;

    for (int i = 0; i < DEPTH; ++i) {
        const float* x_cur = (i == 0) ? x_in : out;
        const float* lw  = ln_w  + (size_t)i * DMODEL;
        const float* lb  = ln_b  + (size_t)i * DMODEL;
        const float* iw  = inw   + (size_t)i * 2 * DINNER * DMODEL;
        const float* cw  = convw + (size_t)i * DINNER * DCONV;
        const float* cb  = convb + (size_t)i * DINNER;
        const float* xw  = xpw   + (size_t)i * DBCW * DINNER;
        const float* dw  = dtw   + (size_t)i * DINNER * DTRANK;
        const float* db  = dtb   + (size_t)i * DINNER;
        const float* Al  = Alog  + (size_t)i * DINNER * DSTATE;
        const float* Dpp = Dp    + (size_t)i * DINNER;
        const float* ow  = outw  + (size_t)i * DMODEL * DINNER;

        // 0. weight conversion (in_proj / out_proj)
        f2bf<<<(n_inw + 255) / 256, blk256, 0, stream>>>(iw, inwbf, n_inw);
        f2bf<<<(n_outw + 255) / 256, blk256, 0, stream>>>(ow, outwbf, n_outw);
        // 1. LayerNorm -> bf16 (into ut region; dead before u_t writes)
        ln_kernel<<<ROWS, blk256, 0, stream>>>(x_cur, lw, lb, xnbf);
        // 2. in_proj (bf16 MFMA): xz = xn @ iw^T
        gemm_bf16<false><<<dim3(2 * DINNER / 128, ROWS / 128), blk256, 0, stream>>>(
            (const u16*)xnbf, DMODEL, (const u16*)inwbf, nullptr, xz, ROWS, 2 * DINNER, DMODEL);
        // 2b. x_proj weights -> bf16 (into inwbf region, now dead)
        f2bf<<<(n_xw + 255) / 256, blk256, 0, stream>>>(xw, (__hip_bfloat16*)xwbf, n_xw);
        // 3. u precompute: ut [b,e,t] + u_re [r,e]
        u_t_kernel<<<dim3(SEQ / 64, DINNER / 64, B_SZ), blk256, 0, stream>>>(xz, cw, cb, ut, u_re);
        // 4. x_proj (bf16 MFMA, N=64): dbc = u_re @ xw^T
        gemm_xp_bf16<<<ROWS / 128, blk256, 0, stream>>>(u_re, xwbf, dbc);
        // 5. delta + B/C precompute (merged) — overwrites u_re region (now dead)
        delta_bct_kernel<<<dim3(DINNER / 64, SEQ / 256, B_SZ), blk256, 0, stream>>>(
            dbc, dw, db, dlt, Bt, Ct);
        // 6. K1: half-sequence scans (2x TLP); carry into dbc region (dead)
        scan_half<<<(B_SZ * DINNER) / 16 * 2, blk256, 0, stream>>>(
            xz, ut, dlt, Bt, Ct, Al, Dpp, carry);
        // 7. cumsum of dl over second half (St into ut region; ut dead after K1)
        cumsum_kernel<<<B_SZ * DINNER, blk256, 0, stream>>>(dlt, St);
        // 8. K2: parallel fixup of second half (RMW yraw in xz)
        fixup_kernel<<<(B_SZ * DINNER) / 16 * 8, blk256, 0, stream>>>(
            xz, Ct, St, carry, Al);
        // 9. gate + pack bf16 y in-place into xz rows (pitch 4096 u16)
        gate_pack<<<ROWS, blk256, 0, stream>>>(xz);
        // 10. out_proj (bf16 MFMA, lda=4096) + residual
        gemm_bf16<true><<<dim3(DMODEL / 128, ROWS / 128), blk256, 0, stream>>>(
            (const u16*)xz, 2 * DINNER * 2, (const u16*)outwbf, x_cur, out, ROWS, DMODEL, DINNER);
    }
}

// Round 10
// 980.029 us; speedup vs baseline: 1.2702x; 1.2702x over previous
//
#include <hip/hip_runtime.h>
#include <hip/hip_bf16.h>
#include <math.h>

// Problem constants
#define B_SZ   8
#define SEQ    2048
#define DMODEL 512
#define DEPTH  2
#define DSTATE 16
#define DCONV  4
#define DINNER 1024
#define DTRANK 32
#define ROWS   (B_SZ * SEQ)          // 16384
#define DBCW   (DTRANK + 2 * DSTATE) // 64

typedef unsigned short u16;
typedef float f32x4 __attribute__((ext_vector_type(4)));
typedef short bf16x8 __attribute__((ext_vector_type(8)));

// Fast device math (native v_exp/v_log/v_rcp)
__device__ __forceinline__ float silu_f(float v) {
    return v * __builtin_amdgcn_rcpf(1.f + __expf(-v));
}
__device__ __forceinline__ float softplus_f(float s) {
    return (s > 20.f) ? s : __logf(1.f + __expf(s));
}
__device__ __forceinline__ u16 f2b(float v) {
    __hip_bfloat16 h = __float2bfloat16(v);
    return *(u16*)&h;
}
__device__ __forceinline__ float b2f(u16 v) {
    __hip_bfloat16 h;
    *(u16*)&h = v;
    return __bfloat162float(h);
}
// sum across the 16-lane state group (DPP row rotate-reduce)
__device__ __forceinline__ float sum16(float x) {
    x += __int_as_float(__builtin_amdgcn_update_dpp(0, __float_as_int(x), 0x121, 0xf, 0xf, true));
    x += __int_as_float(__builtin_amdgcn_update_dpp(0, __float_as_int(x), 0x122, 0xf, 0xf, true));
    x += __int_as_float(__builtin_amdgcn_update_dpp(0, __float_as_int(x), 0x124, 0xf, 0xf, true));
    x += __int_as_float(__builtin_amdgcn_update_dpp(0, __float_as_int(x), 0x128, 0xf, 0xf, true));
    return x;
}

__device__ __forceinline__ void load_lds16(const void* g, void* l) {
    __builtin_amdgcn_global_load_lds(
        (const __attribute__((address_space(1))) unsigned int*)g,
        (__attribute__((address_space(3))) unsigned int*)l, 16, 0, 0);
}

// ---------------------------------------------------------------- fused weight conversion (1 launch/layer)
#define N_INW  (2 * DINNER * DMODEL)   // 2,097,152
#define N_OUTW (DMODEL * DINNER)       // 1,048,576
#define N_XW   (DBCW * DINNER)         //    65,536
__global__ __launch_bounds__(256) void conv_weights(const float* __restrict__ iw,
                                                    const float* __restrict__ ow,
                                                    const float* __restrict__ xw,
                                                    u16* __restrict__ inwbf,
                                                    u16* __restrict__ outwbf,
                                                    u16* __restrict__ xwbf) {
    int i = blockIdx.x * 256 + threadIdx.x;
    if (i < N_INW) inwbf[i] = f2b(iw[i]);
    else if (i < N_INW + N_OUTW) outwbf[i - N_INW] = f2b(ow[i - N_INW]);
    else if (i < N_INW + N_OUTW + N_XW) xwbf[i - N_INW - N_OUTW] = f2b(xw[i - N_INW - N_OUTW]);
}

// ---------------------------------------------------------------- LayerNorm (bf16 out)
__global__ __launch_bounds__(256) void ln_kernel(const float* __restrict__ x,
                                                 const float* __restrict__ w,
                                                 const float* __restrict__ b,
                                                 u16* __restrict__ out) {
    int r = blockIdx.x;
    int tid = threadIdx.x;
    const float* xr = x + (size_t)r * DMODEL;
    float2 v = *(const float2*)(xr + tid * 2);
    float s = v.x + v.y;
    float s2 = v.x * v.x + v.y * v.y;
    #pragma unroll
    for (int off = 1; off < 64; off <<= 1) {
        s  += __shfl_xor(s, off);
        s2 += __shfl_xor(s2, off);
    }
    __shared__ float ws[4], ws2[4];
    int wid = tid >> 6, lane = tid & 63;
    if (lane == 0) { ws[wid] = s; ws2[wid] = s2; }
    __syncthreads();
    float ts = ws[0] + ws[1] + ws[2] + ws[3];
    float ts2 = ws2[0] + ws2[1] + ws2[2] + ws2[3];
    float mean = ts * (1.f / DMODEL);
    float var = ts2 * (1.f / DMODEL) - mean * mean;
    float inv = rsqrtf(var + 1e-5f);
    out[(size_t)r * DMODEL + tid * 2]     = f2b((v.x - mean) * inv * w[tid * 2] + b[tid * 2]);
    out[(size_t)r * DMODEL + tid * 2 + 1] = f2b((v.y - mean) * inv * w[tid * 2 + 1] + b[tid * 2 + 1]);
}

// ---------------------------------------------------------------- in_proj bf16 MFMA GEMM
// xi_re[r,e] = row; sz_re[r,e] = silu(z) — both bf16, written from the epilogue.
// 128x128 tile, BK=32, 256 threads = 4 waves (2x2 of 64x64). N=2048, K=512.
__global__ __launch_bounds__(256) void gemm_in(const u16* __restrict__ A,
                                               const u16* __restrict__ W,
                                               u16* __restrict__ xi_re,
                                               u16* __restrict__ sz_re) {
    __shared__ u16 As[128 * 32];
    __shared__ u16 Bs[128 * 32];
    const int K = DMODEL, N = 2 * DINNER;
    int tid = threadIdx.x;
    int wave = tid >> 6, lane = tid & 63;
    int wm = (wave >> 1) * 64, wn = (wave & 1) * 64;
    int m0 = blockIdx.y * 128, n0 = blockIdx.x * 128;
    int srow = lane >> 2, sseg = lane & 3;
    const u16* Ag = A + (size_t)(m0 + wave * 32 + srow) * K + sseg * 8;
    const u16* Wg = W + (size_t)(n0 + wave * 32 + srow) * K + sseg * 8;
    u16* Asw = As + wave * 32 * 32;
    u16* Bsw = Bs + wave * 32 * 32;

    f32x4 acc[4][4] = {};
    int col = lane & 15, quad = lane >> 4;

    for (int k0 = 0; k0 < K; k0 += 32) {
        __syncthreads();
        load_lds16(Ag + k0, Asw);
        load_lds16(Ag + k0 + (size_t)16 * K, Asw + 16 * 32);
        load_lds16(Wg + k0, Bsw);
        load_lds16(Wg + k0 + (size_t)16 * K, Bsw + 16 * 32);
        __syncthreads();
        bf16x8 af[4], bfr[4];
        #pragma unroll
        for (int i = 0; i < 4; ++i) {
            af[i]  = *(const bf16x8*)(As + (wm + i * 16 + col) * 32 + quad * 8);
            bfr[i] = *(const bf16x8*)(Bs + (wn + i * 16 + col) * 32 + quad * 8);
        }
        #pragma unroll
        for (int i = 0; i < 4; ++i)
            #pragma unroll
            for (int j = 0; j < 4; ++j)
                acc[i][j] = __builtin_amdgcn_mfma_f32_16x16x32_bf16(af[i], bfr[j], acc[i][j], 0, 0, 0);
    }
    // n0 is a multiple of 128, so the whole block is on one side of the xi/z split
    bool is_z = (n0 >= DINNER);
    u16* dst = is_z ? sz_re : xi_re;
    int nb = n0 & (DINNER - 1);
    #pragma unroll
    for (int i = 0; i < 4; ++i) {
        int gm_base = m0 + wm + i * 16 + quad * 4;
        #pragma unroll
        for (int j = 0; j < 4; ++j) {
            int gn = nb + wn + j * 16 + col;
            #pragma unroll
            for (int r = 0; r < 4; ++r) {
                float v = acc[i][j][r];
                if (is_z) v = silu_f(v);
                dst[(size_t)(gm_base + r) * DINNER + gn] = f2b(v);
            }
        }
    }
}

// ---------------------------------------------------------------- out_proj bf16 MFMA GEMM (+residual, fp32 out)
__global__ __launch_bounds__(256) void gemm_out(const u16* __restrict__ A,
                                                const u16* __restrict__ W,
                                                const float* __restrict__ res,
                                                float* __restrict__ C) {
    __shared__ u16 As[128 * 32];
    __shared__ u16 Bs[128 * 32];
    const int K = DINNER, N = DMODEL;
    int tid = threadIdx.x;
    int wave = tid >> 6, lane = tid & 63;
    int wm = (wave >> 1) * 64, wn = (wave & 1) * 64;
    int m0 = blockIdx.y * 128, n0 = blockIdx.x * 128;
    int srow = lane >> 2, sseg = lane & 3;
    const u16* Ag = A + (size_t)(m0 + wave * 32 + srow) * K + sseg * 8;
    const u16* Wg = W + (size_t)(n0 + wave * 32 + srow) * K + sseg * 8;
    u16* Asw = As + wave * 32 * 32;
    u16* Bsw = Bs + wave * 32 * 32;

    f32x4 acc[4][4] = {};
    int col = lane & 15, quad = lane >> 4;

    for (int k0 = 0; k0 < K; k0 += 32) {
        __syncthreads();
        load_lds16(Ag + k0, Asw);
        load_lds16(Ag + k0 + (size_t)16 * K, Asw + 16 * 32);
        load_lds16(Wg + k0, Bsw);
        load_lds16(Wg + k0 + (size_t)16 * K, Bsw + 16 * 32);
        __syncthreads();
        bf16x8 af[4], bfr[4];
        #pragma unroll
        for (int i = 0; i < 4; ++i) {
            af[i]  = *(const bf16x8*)(As + (wm + i * 16 + col) * 32 + quad * 8);
            bfr[i] = *(const bf16x8*)(Bs + (wn + i * 16 + col) * 32 + quad * 8);
        }
        #pragma unroll
        for (int i = 0; i < 4; ++i)
            #pragma unroll
            for (int j = 0; j < 4; ++j)
                acc[i][j] = __builtin_amdgcn_mfma_f32_16x16x32_bf16(af[i], bfr[j], acc[i][j], 0, 0, 0);
    }
    #pragma unroll
    for (int i = 0; i < 4; ++i) {
        int gm_base = m0 + wm + i * 16 + quad * 4;
        #pragma unroll
        for (int j = 0; j < 4; ++j) {
            int gn = n0 + wn + j * 16 + col;
            #pragma unroll
            for (int r = 0; r < 4; ++r) {
                size_t off = (size_t)(gm_base + r) * N + gn;
                C[off] = acc[i][j][r] + res[off];
            }
        }
    }
}

// ---------------------------------------------------------------- x_proj bf16 MFMA GEMM (N=64)
__global__ __launch_bounds__(256) void gemm_xp_bf16(const u16* __restrict__ A,
                                                    const u16* __restrict__ W,
                                                    float* __restrict__ C) {
    __shared__ u16 As[128 * 32];
    __shared__ u16 Bs[64 * 32];
    int tid = threadIdx.x;
    int wave = tid >> 6, lane = tid & 63;
    int m0 = blockIdx.x * 128;
    int wm = wave * 32;
    int srow = lane >> 2, sseg = lane & 3;
    const u16* Ag = A + (size_t)(m0 + wm + srow) * DINNER + sseg * 8;
    const u16* Wg = W + (size_t)(wave * 16 + srow) * DINNER + sseg * 8;
    u16* Asw = As + wave * 32 * 32;
    u16* Bsw = Bs + wave * 16 * 32;

    f32x4 acc[2][4] = {};
    int col = lane & 15, quad = lane >> 4;

    for (int k0 = 0; k0 < DINNER; k0 += 32) {
        __syncthreads();
        load_lds16(Ag + k0, Asw);
        load_lds16(Ag + k0 + (size_t)16 * DINNER, Asw + 16 * 32);
        load_lds16(Wg + k0, Bsw);
        __syncthreads();
        bf16x8 af[2], bfr[4];
        #pragma unroll
        for (int i = 0; i < 2; ++i)
            af[i] = *(const bf16x8*)(As + (wm + i * 16 + col) * 32 + quad * 8);
        #pragma unroll
        for (int j = 0; j < 4; ++j)
            bfr[j] = *(const bf16x8*)(Bs + (j * 16 + col) * 32 + quad * 8);
        #pragma unroll
        for (int i = 0; i < 2; ++i)
            #pragma unroll
            for (int j = 0; j < 4; ++j)
                acc[i][j] = __builtin_amdgcn_mfma_f32_16x16x32_bf16(af[i], bfr[j], acc[i][j], 0, 0, 0);
    }
    #pragma unroll
    for (int i = 0; i < 2; ++i) {
        int gm_base = m0 + wm + i * 16 + quad * 4;
        #pragma unroll
        for (int j = 0; j < 4; ++j) {
            int gn = j * 16 + col;
            #pragma unroll
            for (int r = 0; r < 4; ++r)
                C[(size_t)(gm_base + r) * DBCW + gn] = acc[i][j][r];
        }
    }
}

// ---------------------------------------------------------------- u precompute + sz transpose
// in: xi_re[r,e] bf16, sz_re[r,e] bf16.
// out: ut[b,e,t] bf16, u_re[r,e] bf16, szt[b,e,t] bf16.
// grid: (SEQ/64, DINNER/64, B_SZ), block 256.
__global__ __launch_bounds__(256) void u_t_kernel(const u16* __restrict__ xi_re,
                                                  const u16* __restrict__ sz_re,
                                                  const float* __restrict__ cw,
                                                  const float* __restrict__ cb,
                                                  u16* __restrict__ ut,
                                                  u16* __restrict__ u_re,
                                                  u16* __restrict__ szt) {
    __shared__ float xt[67][65];
    __shared__ u16 uo[64][70];
    __shared__ u16 szo[64][70];
    int tid = threadIdx.x;
    int t0 = blockIdx.x * 64, e0 = blockIdx.y * 64, b = blockIdx.z;
    int er = tid & 63, rr = tid >> 6;
    // xi tile with 3-row halo
    for (int it = 0; it < 17; ++it) {
        int row = it * 4 + rr;
        if (row < 67) {
            int t = t0 + row - 3;
            xt[row][er] = (t >= 0) ? b2f(xi_re[((size_t)b * SEQ + t) * DINNER + e0 + er]) : 0.f;
        }
    }
    // sz tile (transposed into szo[e][t])
    #pragma unroll
    for (int it = 0; it < 16; ++it) {
        int row = it * 4 + rr;
        szo[er][row] = sz_re[((size_t)b * SEQ + t0 + row) * DINNER + e0 + er];
    }
    __syncthreads();
    {
        int e = tid & 63, tg = tid >> 6;
        float4 w4 = *(const float4*)(cw + (e0 + e) * 4);
        float cbe = cb[e0 + e];
        int tl0 = tg * 16;
        float x3 = xt[tl0][e], x2 = xt[tl0 + 1][e], x1 = xt[tl0 + 2][e];
        #pragma unroll
        for (int i = 0; i < 16; ++i) {
            float x0 = xt[tl0 + i + 3][e];
            float u = silu_f(cbe + w4.x * x3 + w4.y * x2 + w4.z * x1 + w4.w * x0);
            x3 = x2; x2 = x1; x1 = x0;
            u16 ub = f2b(u);
            uo[e][tl0 + i] = ub;
            u_re[((size_t)b * SEQ + t0 + tl0 + i) * DINNER + e0 + e] = ub;
        }
    }
    __syncthreads();
    {
        int tl = tid & 63, eg = tid >> 6;
        #pragma unroll
        for (int i = 0; i < 16; ++i) {
            int ee = eg * 16 + i;
            ut[((size_t)b * DINNER + e0 + ee) * SEQ + t0 + tl] = uo[ee][tl];
            szt[((size_t)b * DINNER + e0 + ee) * SEQ + t0 + tl] = szo[ee][tl];
        }
    }
}

// ---------------------------------------------------------------- delta + B/C precompute (merged)
__global__ __launch_bounds__(256) void delta_bct_kernel(const float* __restrict__ dbc,
                                                        const float* __restrict__ dtw,
                                                        const float* __restrict__ dtb,
                                                        u16* __restrict__ dlt,
                                                        u16* __restrict__ Bt,
                                                        u16* __restrict__ Ct) {
    __shared__ float wl[64 * 32];
    __shared__ float bl[64];
    int tid = threadIdx.x;
    int e0 = blockIdx.x * 64, t0 = blockIdx.y * 256, b = blockIdx.z;
    for (int i = tid; i < 64 * 32; i += 256) wl[i] = dtw[(size_t)e0 * DTRANK + i];
    if (tid < 64) bl[tid] = dtb[e0 + tid];
    float dreg[32];
    const float* dp = dbc + (size_t)(b * SEQ + t0 + tid) * DBCW;
    #pragma unroll
    for (int k = 0; k < 32; k += 4) {
        float4 v = *(const float4*)(dp + k);
        dreg[k] = v.x; dreg[k + 1] = v.y; dreg[k + 2] = v.z; dreg[k + 3] = v.w;
    }
    __syncthreads();
    for (int ep = 0; ep < 64; ++ep) {
        float s = bl[ep];
        #pragma unroll
        for (int k = 0; k < 32; ++k) s += dreg[k] * wl[ep * 32 + k];
        dlt[((size_t)b * DINNER + e0 + ep) * SEQ + t0 + tid] = f2b(softplus_f(s));
    }
    if (blockIdx.x == 0) {
        int t = t0 + tid;
        const float* dp2 = dbc + (size_t)(b * SEQ + t) * DBCW + DTRANK;
        #pragma unroll
        for (int nn = 0; nn < DSTATE; ++nn) {
            Bt[((size_t)b * DSTATE + nn) * SEQ + t] = f2b(dp2[nn]);
            Ct[((size_t)b * DSTATE + nn) * SEQ + t] = f2b(dp2[DSTATE + nn]);
        }
    }
}

// ---------------------------------------------------------------- slim selective scan + fused gate
// bf16 t-contiguous inputs; lane n==0 writes final gated bf16 y directly.
// block: 256 threads = 16 (b,e) pairs x 16 states. 512 blocks.
#define SCHUNK 8

__global__ __launch_bounds__(256, 2) void scan_fused(u16* __restrict__ y_re,
                                                     const u16* __restrict__ ut,
                                                     const u16* __restrict__ dlt,
                                                     const u16* __restrict__ Bt,
                                                     const u16* __restrict__ Ct,
                                                     const u16* __restrict__ szt,
                                                     const float* __restrict__ Alog,
                                                     const float* __restrict__ Dp) {
    int tid = threadIdx.x;
    int pair = tid >> 4, n = tid & 15;
    int blk = blockIdx.x;
    int b = blk >> 6;
    int e = ((blk & 63) << 4) + pair;
    float a = -__expf(Alog[e * DSTATE + n]);
    float dpe = Dp[e];
    const u16* urow  = ut  + ((size_t)b * DINNER + e) * SEQ;
    const u16* dlrow = dlt + ((size_t)b * DINNER + e) * SEQ;
    const u16* szrow = szt + ((size_t)b * DINNER + e) * SEQ;
    const u16* Brow  = Bt + ((size_t)b * DSTATE + n) * SEQ;
    const u16* Crow  = Ct + ((size_t)b * DSTATE + n) * SEQ;
    u16* yrow = y_re + (size_t)b * SEQ * DINNER + e;

    float h = 0.f;
    bf16x8 Au, Adl, AB, AC, Asz, Bu, Bdl, BB, BC, Bsz;

    auto load = [&](int c, bf16x8& u8, bf16x8& d8, bf16x8& b8, bf16x8& c8, bf16x8& s8) {
        u8 = *(const bf16x8*)(urow + c * SCHUNK);
        d8 = *(const bf16x8*)(dlrow + c * SCHUNK);
        b8 = *(const bf16x8*)(Brow + c * SCHUNK);
        c8 = *(const bf16x8*)(Crow + c * SCHUNK);
        s8 = *(const bf16x8*)(szrow + c * SCHUNK);
    };
    auto proc = [&](int c, bf16x8 u8, bf16x8 d8, bf16x8 b8, bf16x8 c8, bf16x8 s8) {
        u16* yp_ = yrow + (size_t)c * SCHUNK * DINNER;
        #pragma unroll
        for (int j = 0; j < SCHUNK; ++j) {
            float uf = b2f((u16)u8[j]);
            float dl = b2f((u16)d8[j]);
            float dA = __expf(dl * a);
            h = dA * h + (dl * uf) * b2f((u16)b8[j]);
            float yp = sum16(h * b2f((u16)c8[j]));
            if (n == 0)
                yp_[(size_t)j * DINNER] = f2b((yp + uf * dpe) * b2f((u16)s8[j]));
        }
    };

    const int nc = SEQ / SCHUNK;   // 256, even
    load(0, Au, Adl, AB, AC, Asz);
    for (int c = 0; c < nc; c += 2) {
        load(c + 1, Bu, Bdl, BB, BC, Bsz);
        proc(c, Au, Adl, AB, AC, Asz);
        if (c + 2 < nc) load(c + 2, Au, Adl, AB, AC, Asz);
        proc(c + 1, Bu, Bdl, BB, BC, Bsz);
    }
}

// ---------------------------------------------------------------- launch
extern "C" void kernel_launch(void* const* d_in, const int* in_sizes, int n_in,
                              void* d_out, int out_size, void* d_ws, size_t ws_size,
                              hipStream_t stream) {
    const float* x_in   = (const float*)d_in[0];
    const float* ln_w   = (const float*)d_in[1];
    const float* ln_b   = (const float*)d_in[2];
    const float* inw    = (const float*)d_in[3];
    const float* convw  = (const float*)d_in[4];
    const float* convb  = (const float*)d_in[5];
    const float* xpw    = (const float*)d_in[6];
    const float* dtw    = (const float*)d_in[7];
    const float* dtb    = (const float*)d_in[8];
    const float* Alog   = (const float*)d_in[9];
    const float* Dp     = (const float*)d_in[10];
    const float* outw   = (const float*)d_in[11];
    float* out = (float*)d_out;

    // workspace carve-up — 212,860,928 B (exactly the proven footprint)
    char* p = (char*)d_ws;
    u16* xi_re = (u16*)p;               p += (size_t)ROWS * DINNER * 2;          //  33,554,432
    u16* sz_re = (u16*)p;               p += (size_t)ROWS * DINNER * 2;          //  33,554,432
    u16* y_re  = (u16*)p;               p += (size_t)ROWS * DINNER * 2;          //  33,554,432
    float* dbc = (float*)p;             p += (size_t)ROWS * DBCW * 4;            //   4,194,304
    u16* dlt   = (u16*)p;               p += (size_t)B_SZ * DINNER * SEQ * 2;    //  33,554,432
    u16* u_re  = dlt;                   // alias: u_re consumed by gemm_xp before delta writes dlt
    u16* Bt    = (u16*)p;               p += (size_t)B_SZ * DSTATE * SEQ * 2;    //     524,288
    u16* xwbf  = Bt;                    // alias: xwbf consumed by gemm_xp before delta_bct writes Bt
    u16* Ct    = (u16*)p;               p += (size_t)B_SZ * DSTATE * SEQ * 2;    //     524,288
    u16* ut    = (u16*)p;               p += (size_t)B_SZ * DINNER * SEQ * 2;    //  33,554,432
    u16* xnbf  = ut;                    // alias: xn (16.8 MB) dead before u_t writes ut
    u16* szt   = (u16*)p;               p += (size_t)B_SZ * DINNER * SEQ * 2;    //  33,554,432
    u16* inwbf = (u16*)p;               p += (size_t)N_INW * 2;                  //   4,194,304
    u16* outwbf = (u16*)p;              p += (size_t)N_OUTW * 2;                 //   2,097,152

    const dim3 blk256(256);
    const int n_conv = N_INW + N_OUTW + N_XW;

    for (int i = 0; i < DEPTH; ++i) {
        const float* x_cur = (i == 0) ? x_in : out;
        const float* lw  = ln_w  + (size_t)i * DMODEL;
        const float* lb  = ln_b  + (size_t)i * DMODEL;
        const float* iw  = inw   + (size_t)i * 2 * DINNER * DMODEL;
        const float* cw  = convw + (size_t)i * DINNER * DCONV;
        const float* cb  = convb + (size_t)i * DINNER;
        const float* xw  = xpw   + (size_t)i * DBCW * DINNER;
        const float* dw  = dtw   + (size_t)i * DINNER * DTRANK;
        const float* db  = dtb   + (size_t)i * DINNER;
        const float* Al  = Alog  + (size_t)i * DINNER * DSTATE;
        const float* Dpp = Dp    + (size_t)i * DINNER;
        const float* ow  = outw  + (size_t)i * DMODEL * DINNER;

        // 0. all weight conversions in one launch (xwbf parked in Bt region)
        conv_weights<<<(n_conv + 255) / 256, blk256, 0, stream>>>(
            iw, ow, xw, inwbf, outwbf, xwbf);
        // 1. LayerNorm -> bf16 (into ut region; dead before u_t writes)
        ln_kernel<<<ROWS, blk256, 0, stream>>>(x_cur, lw, lb, xnbf);
        // 2. in_proj (bf16 MFMA): xi_re = xn@iw_x^T, sz_re = silu(xn@iw_z^T)
        gemm_in<<<dim3(2 * DINNER / 128, ROWS / 128), blk256, 0, stream>>>(
            xnbf, inwbf, xi_re, sz_re);
        // 3. u precompute: ut[b,e,t] + u_re[r,e] + szt[b,e,t]
        u_t_kernel<<<dim3(SEQ / 64, DINNER / 64, B_SZ), blk256, 0, stream>>>(
            xi_re, sz_re, cw, cb, ut, u_re, szt);
        // 4. x_proj (bf16 MFMA, N=64): dbc = u_re @ xw^T
        gemm_xp_bf16<<<ROWS / 128, blk256, 0, stream>>>(u_re, xwbf, dbc);
        // 5. delta + B/C precompute (overwrites u_re/xwbf regions, now dead)
        delta_bct_kernel<<<dim3(DINNER / 64, SEQ / 256, B_SZ), blk256, 0, stream>>>(
            dbc, dw, db, dlt, Bt, Ct);
        // 6. scan + fused gate: y_re bf16 written directly
        scan_fused<<<(B_SZ * DINNER) / 16, blk256, 0, stream>>>(
            y_re, ut, dlt, Bt, Ct, szt, Al, Dpp);
        // 7. out_proj (bf16 MFMA) + residual
        gemm_out<<<dim3(DMODEL / 128, ROWS / 128), blk256, 0, stream>>>(
            y_re, outwbf, x_cur, out);
    }
}

// Round 11
// 853.905 us; speedup vs baseline: 1.4578x; 1.1477x over previous
//
#include <hip/hip_runtime.h>
#include <hip/hip_bf16.h>
#include <math.h>

// Problem constants
#define B_SZ   8
#define SEQ    2048
#define DMODEL 512
#define DEPTH  2
#define DSTATE 16
#define DCONV  4
#define DINNER 1024
#define DTRANK 32
#define ROWS   (B_SZ * SEQ)          // 16384
#define DBCW   (DTRANK + 2 * DSTATE) // 64

typedef unsigned short u16;
typedef float f32x4 __attribute__((ext_vector_type(4)));
typedef short bf16x8 __attribute__((ext_vector_type(8)));

// Fast device math (native v_exp/v_log/v_rcp)
__device__ __forceinline__ float silu_f(float v) {
    return v * __builtin_amdgcn_rcpf(1.f + __expf(-v));
}
__device__ __forceinline__ float softplus_f(float s) {
    return (s > 20.f) ? s : __logf(1.f + __expf(s));
}
__device__ __forceinline__ u16 f2b(float v) {
    __hip_bfloat16 h = __float2bfloat16(v);
    return *(u16*)&h;
}
__device__ __forceinline__ float b2f(u16 v) {
    __hip_bfloat16 h;
    *(u16*)&h = v;
    return __bfloat162float(h);
}
// sum across the 16-lane state group (DPP row rotate-reduce; all 16 lanes end with the total)
__device__ __forceinline__ float sum16(float x) {
    x += __int_as_float(__builtin_amdgcn_update_dpp(0, __float_as_int(x), 0x121, 0xf, 0xf, true));
    x += __int_as_float(__builtin_amdgcn_update_dpp(0, __float_as_int(x), 0x122, 0xf, 0xf, true));
    x += __int_as_float(__builtin_amdgcn_update_dpp(0, __float_as_int(x), 0x124, 0xf, 0xf, true));
    x += __int_as_float(__builtin_amdgcn_update_dpp(0, __float_as_int(x), 0x128, 0xf, 0xf, true));
    return x;
}

__device__ __forceinline__ void load_lds16(const void* g, void* l) {
    __builtin_amdgcn_global_load_lds(
        (const __attribute__((address_space(1))) unsigned int*)g,
        (__attribute__((address_space(3))) unsigned int*)l, 16, 0, 0);
}

// ---------------------------------------------------------------- fused weight conversion (1 launch/layer)
#define N_INW  (2 * DINNER * DMODEL)   // 2,097,152
#define N_OUTW (DMODEL * DINNER)       // 1,048,576
#define N_XW   (DBCW * DINNER)         //    65,536
__global__ __launch_bounds__(256) void conv_weights(const float* __restrict__ iw,
                                                    const float* __restrict__ ow,
                                                    const float* __restrict__ xw,
                                                    u16* __restrict__ inwbf,
                                                    u16* __restrict__ outwbf,
                                                    u16* __restrict__ xwbf) {
    int i = blockIdx.x * 256 + threadIdx.x;
    if (i < N_INW) inwbf[i] = f2b(iw[i]);
    else if (i < N_INW + N_OUTW) outwbf[i - N_INW] = f2b(ow[i - N_INW]);
    else if (i < N_INW + N_OUTW + N_XW) xwbf[i - N_INW - N_OUTW] = f2b(xw[i - N_INW - N_OUTW]);
}

// ---------------------------------------------------------------- LayerNorm (bf16 out)
__global__ __launch_bounds__(256) void ln_kernel(const float* __restrict__ x,
                                                 const float* __restrict__ w,
                                                 const float* __restrict__ b,
                                                 u16* __restrict__ out) {
    int r = blockIdx.x;
    int tid = threadIdx.x;
    const float* xr = x + (size_t)r * DMODEL;
    float2 v = *(const float2*)(xr + tid * 2);
    float s = v.x + v.y;
    float s2 = v.x * v.x + v.y * v.y;
    #pragma unroll
    for (int off = 1; off < 64; off <<= 1) {
        s  += __shfl_xor(s, off);
        s2 += __shfl_xor(s2, off);
    }
    __shared__ float ws[4], ws2[4];
    int wid = tid >> 6, lane = tid & 63;
    if (lane == 0) { ws[wid] = s; ws2[wid] = s2; }
    __syncthreads();
    float ts = ws[0] + ws[1] + ws[2] + ws[3];
    float ts2 = ws2[0] + ws2[1] + ws2[2] + ws2[3];
    float mean = ts * (1.f / DMODEL);
    float var = ts2 * (1.f / DMODEL) - mean * mean;
    float inv = rsqrtf(var + 1e-5f);
    out[(size_t)r * DMODEL + tid * 2]     = f2b((v.x - mean) * inv * w[tid * 2] + b[tid * 2]);
    out[(size_t)r * DMODEL + tid * 2 + 1] = f2b((v.y - mean) * inv * w[tid * 2 + 1] + b[tid * 2 + 1]);
}

// ---------------------------------------------------------------- in_proj bf16 MFMA GEMM
// xi_re[r,e]; sz_re[r,e] = silu(z) — both bf16, written from the epilogue.
__global__ __launch_bounds__(256) void gemm_in(const u16* __restrict__ A,
                                               const u16* __restrict__ W,
                                               u16* __restrict__ xi_re,
                                               u16* __restrict__ sz_re) {
    __shared__ u16 As[128 * 32];
    __shared__ u16 Bs[128 * 32];
    const int K = DMODEL;
    int tid = threadIdx.x;
    int wave = tid >> 6, lane = tid & 63;
    int wm = (wave >> 1) * 64, wn = (wave & 1) * 64;
    int m0 = blockIdx.y * 128, n0 = blockIdx.x * 128;
    int srow = lane >> 2, sseg = lane & 3;
    const u16* Ag = A + (size_t)(m0 + wave * 32 + srow) * K + sseg * 8;
    const u16* Wg = W + (size_t)(n0 + wave * 32 + srow) * K + sseg * 8;
    u16* Asw = As + wave * 32 * 32;
    u16* Bsw = Bs + wave * 32 * 32;

    f32x4 acc[4][4] = {};
    int col = lane & 15, quad = lane >> 4;

    for (int k0 = 0; k0 < K; k0 += 32) {
        __syncthreads();
        load_lds16(Ag + k0, Asw);
        load_lds16(Ag + k0 + (size_t)16 * K, Asw + 16 * 32);
        load_lds16(Wg + k0, Bsw);
        load_lds16(Wg + k0 + (size_t)16 * K, Bsw + 16 * 32);
        __syncthreads();
        bf16x8 af[4], bfr[4];
        #pragma unroll
        for (int i = 0; i < 4; ++i) {
            af[i]  = *(const bf16x8*)(As + (wm + i * 16 + col) * 32 + quad * 8);
            bfr[i] = *(const bf16x8*)(Bs + (wn + i * 16 + col) * 32 + quad * 8);
        }
        #pragma unroll
        for (int i = 0; i < 4; ++i)
            #pragma unroll
            for (int j = 0; j < 4; ++j)
                acc[i][j] = __builtin_amdgcn_mfma_f32_16x16x32_bf16(af[i], bfr[j], acc[i][j], 0, 0, 0);
    }
    bool is_z = (n0 >= DINNER);
    u16* dst = is_z ? sz_re : xi_re;
    int nb = n0 & (DINNER - 1);
    #pragma unroll
    for (int i = 0; i < 4; ++i) {
        int gm_base = m0 + wm + i * 16 + quad * 4;
        #pragma unroll
        for (int j = 0; j < 4; ++j) {
            int gn = nb + wn + j * 16 + col;
            #pragma unroll
            for (int r = 0; r < 4; ++r) {
                float v = acc[i][j][r];
                if (is_z) v = silu_f(v);
                dst[(size_t)(gm_base + r) * DINNER + gn] = f2b(v);
            }
        }
    }
}

// ---------------------------------------------------------------- out_proj bf16 MFMA GEMM (+residual, fp32 out)
__global__ __launch_bounds__(256) void gemm_out(const u16* __restrict__ A,
                                                const u16* __restrict__ W,
                                                const float* __restrict__ res,
                                                float* __restrict__ C) {
    __shared__ u16 As[128 * 32];
    __shared__ u16 Bs[128 * 32];
    const int K = DINNER, N = DMODEL;
    int tid = threadIdx.x;
    int wave = tid >> 6, lane = tid & 63;
    int wm = (wave >> 1) * 64, wn = (wave & 1) * 64;
    int m0 = blockIdx.y * 128, n0 = blockIdx.x * 128;
    int srow = lane >> 2, sseg = lane & 3;
    const u16* Ag = A + (size_t)(m0 + wave * 32 + srow) * K + sseg * 8;
    const u16* Wg = W + (size_t)(n0 + wave * 32 + srow) * K + sseg * 8;
    u16* Asw = As + wave * 32 * 32;
    u16* Bsw = Bs + wave * 32 * 32;

    f32x4 acc[4][4] = {};
    int col = lane & 15, quad = lane >> 4;

    for (int k0 = 0; k0 < K; k0 += 32) {
        __syncthreads();
        load_lds16(Ag + k0, Asw);
        load_lds16(Ag + k0 + (size_t)16 * K, Asw + 16 * 32);
        load_lds16(Wg + k0, Bsw);
        load_lds16(Wg + k0 + (size_t)16 * K, Bsw + 16 * 32);
        __syncthreads();
        bf16x8 af[4], bfr[4];
        #pragma unroll
        for (int i = 0; i < 4; ++i) {
            af[i]  = *(const bf16x8*)(As + (wm + i * 16 + col) * 32 + quad * 8);
            bfr[i] = *(const bf16x8*)(Bs + (wn + i * 16 + col) * 32 + quad * 8);
        }
        #pragma unroll
        for (int i = 0; i < 4; ++i)
            #pragma unroll
            for (int j = 0; j < 4; ++j)
                acc[i][j] = __builtin_amdgcn_mfma_f32_16x16x32_bf16(af[i], bfr[j], acc[i][j], 0, 0, 0);
    }
    #pragma unroll
    for (int i = 0; i < 4; ++i) {
        int gm_base = m0 + wm + i * 16 + quad * 4;
        #pragma unroll
        for (int j = 0; j < 4; ++j) {
            int gn = n0 + wn + j * 16 + col;
            #pragma unroll
            for (int r = 0; r < 4; ++r) {
                size_t off = (size_t)(gm_base + r) * N + gn;
                C[off] = acc[i][j][r] + res[off];
            }
        }
    }
}

// ---------------------------------------------------------------- x_proj bf16 MFMA GEMM (N=64)
__global__ __launch_bounds__(256) void gemm_xp_bf16(const u16* __restrict__ A,
                                                    const u16* __restrict__ W,
                                                    float* __restrict__ C) {
    __shared__ u16 As[128 * 32];
    __shared__ u16 Bs[64 * 32];
    int tid = threadIdx.x;
    int wave = tid >> 6, lane = tid & 63;
    int m0 = blockIdx.x * 128;
    int wm = wave * 32;
    int srow = lane >> 2, sseg = lane & 3;
    const u16* Ag = A + (size_t)(m0 + wm + srow) * DINNER + sseg * 8;
    const u16* Wg = W + (size_t)(wave * 16 + srow) * DINNER + sseg * 8;
    u16* Asw = As + wave * 32 * 32;
    u16* Bsw = Bs + wave * 16 * 32;

    f32x4 acc[2][4] = {};
    int col = lane & 15, quad = lane >> 4;

    for (int k0 = 0; k0 < DINNER; k0 += 32) {
        __syncthreads();
        load_lds16(Ag + k0, Asw);
        load_lds16(Ag + k0 + (size_t)16 * DINNER, Asw + 16 * 32);
        load_lds16(Wg + k0, Bsw);
        __syncthreads();
        bf16x8 af[2], bfr[4];
        #pragma unroll
        for (int i = 0; i < 2; ++i)
            af[i] = *(const bf16x8*)(As + (wm + i * 16 + col) * 32 + quad * 8);
        #pragma unroll
        for (int j = 0; j < 4; ++j)
            bfr[j] = *(const bf16x8*)(Bs + (j * 16 + col) * 32 + quad * 8);
        #pragma unroll
        for (int i = 0; i < 2; ++i)
            #pragma unroll
            for (int j = 0; j < 4; ++j)
                acc[i][j] = __builtin_amdgcn_mfma_f32_16x16x32_bf16(af[i], bfr[j], acc[i][j], 0, 0, 0);
    }
    #pragma unroll
    for (int i = 0; i < 2; ++i) {
        int gm_base = m0 + wm + i * 16 + quad * 4;
        #pragma unroll
        for (int j = 0; j < 4; ++j) {
            int gn = j * 16 + col;
            #pragma unroll
            for (int r = 0; r < 4; ++r)
                C[(size_t)(gm_base + r) * DBCW + gn] = acc[i][j][r];
        }
    }
}

// ---------------------------------------------------------------- u precompute + sz transpose
__global__ __launch_bounds__(256) void u_t_kernel(const u16* __restrict__ xi_re,
                                                  const u16* __restrict__ sz_re,
                                                  const float* __restrict__ cw,
                                                  const float* __restrict__ cb,
                                                  u16* __restrict__ ut,
                                                  u16* __restrict__ u_re,
                                                  u16* __restrict__ szt) {
    __shared__ float xt[67][65];
    __shared__ u16 uo[64][70];
    __shared__ u16 szo[64][70];
    int tid = threadIdx.x;
    int t0 = blockIdx.x * 64, e0 = blockIdx.y * 64, b = blockIdx.z;
    int er = tid & 63, rr = tid >> 6;
    for (int it = 0; it < 17; ++it) {
        int row = it * 4 + rr;
        if (row < 67) {
            int t = t0 + row - 3;
            xt[row][er] = (t >= 0) ? b2f(xi_re[((size_t)b * SEQ + t) * DINNER + e0 + er]) : 0.f;
        }
    }
    #pragma unroll
    for (int it = 0; it < 16; ++it) {
        int row = it * 4 + rr;
        szo[er][row] = sz_re[((size_t)b * SEQ + t0 + row) * DINNER + e0 + er];
    }
    __syncthreads();
    {
        int e = tid & 63, tg = tid >> 6;
        float4 w4 = *(const float4*)(cw + (e0 + e) * 4);
        float cbe = cb[e0 + e];
        int tl0 = tg * 16;
        float x3 = xt[tl0][e], x2 = xt[tl0 + 1][e], x1 = xt[tl0 + 2][e];
        #pragma unroll
        for (int i = 0; i < 16; ++i) {
            float x0 = xt[tl0 + i + 3][e];
            float u = silu_f(cbe + w4.x * x3 + w4.y * x2 + w4.z * x1 + w4.w * x0);
            x3 = x2; x2 = x1; x1 = x0;
            u16 ub = f2b(u);
            uo[e][tl0 + i] = ub;
            u_re[((size_t)b * SEQ + t0 + tl0 + i) * DINNER + e0 + e] = ub;
        }
    }
    __syncthreads();
    {
        int tl = tid & 63, eg = tid >> 6;
        #pragma unroll
        for (int i = 0; i < 16; ++i) {
            int ee = eg * 16 + i;
            ut[((size_t)b * DINNER + e0 + ee) * SEQ + t0 + tl] = uo[ee][tl];
            szt[((size_t)b * DINNER + e0 + ee) * SEQ + t0 + tl] = szo[ee][tl];
        }
    }
}

// ---------------------------------------------------------------- delta + B/C precompute (merged)
__global__ __launch_bounds__(256) void delta_bct_kernel(const float* __restrict__ dbc,
                                                        const float* __restrict__ dtw,
                                                        const float* __restrict__ dtb,
                                                        u16* __restrict__ dlt,
                                                        u16* __restrict__ Bt,
                                                        u16* __restrict__ Ct) {
    __shared__ float wl[64 * 32];
    __shared__ float bl[64];
    int tid = threadIdx.x;
    int e0 = blockIdx.x * 64, t0 = blockIdx.y * 256, b = blockIdx.z;
    for (int i = tid; i < 64 * 32; i += 256) wl[i] = dtw[(size_t)e0 * DTRANK + i];
    if (tid < 64) bl[tid] = dtb[e0 + tid];
    float dreg[32];
    const float* dp = dbc + (size_t)(b * SEQ + t0 + tid) * DBCW;
    #pragma unroll
    for (int k = 0; k < 32; k += 4) {
        float4 v = *(const float4*)(dp + k);
        dreg[k] = v.x; dreg[k + 1] = v.y; dreg[k + 2] = v.z; dreg[k + 3] = v.w;
    }
    __syncthreads();
    for (int ep = 0; ep < 64; ++ep) {
        float s = bl[ep];
        #pragma unroll
        for (int k = 0; k < 32; ++k) s += dreg[k] * wl[ep * 32 + k];
        dlt[((size_t)b * DINNER + e0 + ep) * SEQ + t0 + tid] = f2b(softplus_f(s));
    }
    if (blockIdx.x == 0) {
        int t = t0 + tid;
        const float* dp2 = dbc + (size_t)(b * SEQ + t) * DBCW + DTRANK;
        #pragma unroll
        for (int nn = 0; nn < DSTATE; ++nn) {
            Bt[((size_t)b * DSTATE + nn) * SEQ + t] = f2b(dp2[nn]);
            Ct[((size_t)b * DSTATE + nn) * SEQ + t] = f2b(dp2[DSTATE + nn]);
        }
    }
}

// ---------------------------------------------------------------- slim selective scan + register-keep gated output
// Per t: cvt x4, exp2, 4 fma/mul, sum16 (4 DPP), cmp+cndmask keep. Gate+store
// happen once per 16-t chunk with ALL lanes active (lane n stores t = c*16+n).
// block: 256 threads = 16 (b,e) pairs x 16 states. 512 blocks.
#define SCHUNK 16

__global__ __launch_bounds__(256, 2) void scan_fused(u16* __restrict__ y_re,
                                                     const u16* __restrict__ ut,
                                                     const u16* __restrict__ dlt,
                                                     const u16* __restrict__ Bt,
                                                     const u16* __restrict__ Ct,
                                                     const u16* __restrict__ szt,
                                                     const float* __restrict__ Alog,
                                                     const float* __restrict__ Dp) {
    int tid = threadIdx.x;
    int pair = tid >> 4, n = tid & 15;
    int blk = blockIdx.x;
    int b = blk >> 6;
    int e = ((blk & 63) << 4) + pair;
    float a2 = -__expf(Alog[e * DSTATE + n]) * 1.44269504f;   // fold log2e: dA = exp2(dl*a2)
    float dpe = Dp[e];
    const u16* urow  = ut  + ((size_t)b * DINNER + e) * SEQ;
    const u16* dlrow = dlt + ((size_t)b * DINNER + e) * SEQ;
    const u16* szrow = szt + ((size_t)b * DINNER + e) * SEQ;
    const u16* Brow  = Bt + ((size_t)b * DSTATE + n) * SEQ;
    const u16* Crow  = Ct + ((size_t)b * DSTATE + n) * SEQ;
    // lane n stores t = c*16+n for its pair: scatter over 16 rows
    u16* ystore = y_re + ((size_t)b * SEQ + n) * DINNER + e;

    float h = 0.f;
    bf16x8 Au0, Au1, Adl0, Adl1, AB0, AB1, AC0, AC1;
    bf16x8 Bu0, Bu1, Bdl0, Bdl1, BB0, BB1, BC0, BC1;
    float Asz, Bsz;

    auto load = [&](int c, bf16x8& u0, bf16x8& u1, bf16x8& d0, bf16x8& d1,
                    bf16x8& b0, bf16x8& b1, bf16x8& c0, bf16x8& c1, float& sz) {
        u0 = *(const bf16x8*)(urow + c * SCHUNK);
        u1 = *(const bf16x8*)(urow + c * SCHUNK + 8);
        d0 = *(const bf16x8*)(dlrow + c * SCHUNK);
        d1 = *(const bf16x8*)(dlrow + c * SCHUNK + 8);
        b0 = *(const bf16x8*)(Brow + c * SCHUNK);
        b1 = *(const bf16x8*)(Brow + c * SCHUNK + 8);
        c0 = *(const bf16x8*)(Crow + c * SCHUNK);
        c1 = *(const bf16x8*)(Crow + c * SCHUNK + 8);
        sz = b2f(szrow[c * SCHUNK + n]);   // lane n's own t
    };
    auto proc = [&](int c, bf16x8 u0, bf16x8 u1, bf16x8 d0, bf16x8 d1,
                    bf16x8 b0, bf16x8 b1, bf16x8 c0, bf16x8 c1, float sz) {
        float keep = 0.f;
        #pragma unroll
        for (int j = 0; j < SCHUNK; ++j) {
            float uf = b2f((u16)((j < 8) ? u0[j] : u1[j - 8]));
            float dl = b2f((u16)((j < 8) ? d0[j] : d1[j - 8]));
            float dA = __builtin_amdgcn_exp2f(dl * a2);
            h = dA * h + (dl * uf) * b2f((u16)((j < 8) ? b0[j] : b1[j - 8]));
            float yp = sum16(h * b2f((u16)((j < 8) ? c0[j] : c1[j - 8])));
            float yg = yp + uf * dpe;
            keep = (n == j) ? yg : keep;   // lane n keeps its own t's value
        }
        ystore[(size_t)c * SCHUNK * DINNER] = f2b(keep * sz);
    };

    const int nc = SEQ / SCHUNK;   // 128, even
    load(0, Au0, Au1, Adl0, Adl1, AB0, AB1, AC0, AC1, Asz);
    for (int c = 0; c < nc; c += 2) {
        load(c + 1, Bu0, Bu1, Bdl0, Bdl1, BB0, BB1, BC0, BC1, Bsz);
        proc(c, Au0, Au1, Adl0, Adl1, AB0, AB1, AC0, AC1, Asz);
        if (c + 2 < nc) load(c + 2, Au0, Au1, Adl0, Adl1, AB0, AB1, AC0, AC1, Asz);
        proc(c + 1, Bu0, Bu1, Bdl0, Bdl1, BB0, BB1, BC0, BC1, Bsz);
    }
}

// ---------------------------------------------------------------- launch
extern "C" void kernel_launch(void* const* d_in, const int* in_sizes, int n_in,
                              void* d_out, int out_size, void* d_ws, size_t ws_size,
                              hipStream_t stream) {
    const float* x_in   = (const float*)d_in[0];
    const float* ln_w   = (const float*)d_in[1];
    const float* ln_b   = (const float*)d_in[2];
    const float* inw    = (const float*)d_in[3];
    const float* convw  = (const float*)d_in[4];
    const float* convb  = (const float*)d_in[5];
    const float* xpw    = (const float*)d_in[6];
    const float* dtw    = (const float*)d_in[7];
    const float* dtb    = (const float*)d_in[8];
    const float* Alog   = (const float*)d_in[9];
    const float* Dp     = (const float*)d_in[10];
    const float* outw   = (const float*)d_in[11];
    float* out = (float*)d_out;

    // workspace carve-up — 212,860,928 B (exactly the proven footprint)
    char* p = (char*)d_ws;
    u16* xi_re = (u16*)p;               p += (size_t)ROWS * DINNER * 2;          //  33,554,432
    u16* sz_re = (u16*)p;               p += (size_t)ROWS * DINNER * 2;          //  33,554,432
    u16* y_re  = (u16*)p;               p += (size_t)ROWS * DINNER * 2;          //  33,554,432
    float* dbc = (float*)p;             p += (size_t)ROWS * DBCW * 4;            //   4,194,304
    u16* dlt   = (u16*)p;               p += (size_t)B_SZ * DINNER * SEQ * 2;    //  33,554,432
    u16* u_re  = dlt;                   // alias: u_re consumed by gemm_xp before delta writes dlt
    u16* Bt    = (u16*)p;               p += (size_t)B_SZ * DSTATE * SEQ * 2;    //     524,288
    u16* xwbf  = Bt;                    // alias: xwbf consumed by gemm_xp before delta_bct writes Bt
    u16* Ct    = (u16*)p;               p += (size_t)B_SZ * DSTATE * SEQ * 2;    //     524,288
    u16* ut    = (u16*)p;               p += (size_t)B_SZ * DINNER * SEQ * 2;    //  33,554,432
    u16* xnbf  = ut;                    // alias: xn (16.8 MB) dead before u_t writes ut
    u16* szt   = (u16*)p;               p += (size_t)B_SZ * DINNER * SEQ * 2;    //  33,554,432
    u16* inwbf = (u16*)p;               p += (size_t)N_INW * 2;                  //   4,194,304
    u16* outwbf = (u16*)p;              p += (size_t)N_OUTW * 2;                 //   2,097,152

    const dim3 blk256(256);
    const int n_conv = N_INW + N_OUTW + N_XW;

    for (int i = 0; i < DEPTH; ++i) {
        const float* x_cur = (i == 0) ? x_in : out;
        const float* lw  = ln_w  + (size_t)i * DMODEL;
        const float* lb  = ln_b  + (size_t)i * DMODEL;
        const float* iw  = inw   + (size_t)i * 2 * DINNER * DMODEL;
        const float* cw  = convw + (size_t)i * DINNER * DCONV;
        const float* cb  = convb + (size_t)i * DINNER;
        const float* xw  = xpw   + (size_t)i * DBCW * DINNER;
        const float* dw  = dtw   + (size_t)i * DINNER * DTRANK;
        const float* db  = dtb   + (size_t)i * DINNER;
        const float* Al  = Alog  + (size_t)i * DINNER * DSTATE;
        const float* Dpp = Dp    + (size_t)i * DINNER;
        const float* ow  = outw  + (size_t)i * DMODEL * DINNER;

        // 0. all weight conversions in one launch (xwbf parked in Bt region)
        conv_weights<<<(n_conv + 255) / 256, blk256, 0, stream>>>(
            iw, ow, xw, inwbf, outwbf, xwbf);
        // 1. LayerNorm -> bf16 (into ut region; dead before u_t writes)
        ln_kernel<<<ROWS, blk256, 0, stream>>>(x_cur, lw, lb, xnbf);
        // 2. in_proj (bf16 MFMA): xi_re = xn@iw_x^T, sz_re = silu(xn@iw_z^T)
        gemm_in<<<dim3(2 * DINNER / 128, ROWS / 128), blk256, 0, stream>>>(
            xnbf, inwbf, xi_re, sz_re);
        // 3. u precompute: ut[b,e,t] + u_re[r,e] + szt[b,e,t]
        u_t_kernel<<<dim3(SEQ / 64, DINNER / 64, B_SZ), blk256, 0, stream>>>(
            xi_re, sz_re, cw, cb, ut, u_re, szt);
        // 4. x_proj (bf16 MFMA, N=64): dbc = u_re @ xw^T
        gemm_xp_bf16<<<ROWS / 128, blk256, 0, stream>>>(u_re, xwbf, dbc);
        // 5. delta + B/C precompute (overwrites u_re/xwbf regions, now dead)
        delta_bct_kernel<<<dim3(DINNER / 64, SEQ / 256, B_SZ), blk256, 0, stream>>>(
            dbc, dw, db, dlt, Bt, Ct);
        // 6. scan + register-keep gated output: y_re bf16
        scan_fused<<<(B_SZ * DINNER) / 16, blk256, 0, stream>>>(
            y_re, ut, dlt, Bt, Ct, szt, Al, Dpp);
        // 7. out_proj (bf16 MFMA) + residual
        gemm_out<<<dim3(DMODEL / 128, ROWS / 128), blk256, 0, stream>>>(
            y_re, outwbf, x_cur, out);
    }
}